// Round 12
// baseline (175.945 us; speedup 1.0000x reference)
//
#include <hip/hip_runtime.h>

#define T_STEPS 200
#define IN_DIM 1086
#define KTILES 34              // K padded to 1088
#define M_TOTAL 51200          // 256*200
#define ASTRIDE 1096           // LDS A row stride in bf16 (2192B: 16B-aligned, s-slot balanced)

using f32x4v  = __attribute__((ext_vector_type(4))) float;
using bf16x8  = __attribute__((ext_vector_type(8))) short;
typedef unsigned uv2 __attribute__((ext_vector_type(2)));

#if __has_builtin(__builtin_amdgcn_permlane16_swap) && __has_builtin(__builtin_amdgcn_permlane32_swap)
#define HAVE_PERMLANE_SWAP 1
#else
#define HAVE_PERMLANE_SWAP 0
#endif

#if __has_builtin(__builtin_amdgcn_exp2f)
#define EXP2F(x) __builtin_amdgcn_exp2f(x)
#else
#define EXP2F(x) exp2f(x)
#endif

__device__ __forceinline__ float rl_f(float v, int lane) {
    return __uint_as_float((unsigned)__builtin_amdgcn_readlane((int)__float_as_uint(v), lane));
}

// ---------------------------------------------------------------------------
// prepack_w: W_ih0[64][1086] fp32 -> hi/lo bf16, frag layout [kt][kg][64][8],
// zero-padded to K=1088 (A-tail x*0=0). L2-resident.
// ---------------------------------------------------------------------------
__global__ __launch_bounds__(256) void prepack_w(
    const float* __restrict__ W,
    unsigned short* __restrict__ Wh, unsigned short* __restrict__ Wl)
{
    int idx = blockIdx.x * 256 + threadIdx.x;
    if (idx >= KTILES * 4 * 64 * 8) return;
    int j = idx & 7;
    int n = (idx >> 3) & 63;
    int k = (idx >> 9) * 8 + j;
    float v = (k < IN_DIM) ? W[n * IN_DIM + k] : 0.0f;
    unsigned u = __float_as_uint(v);
    unsigned hi = u & 0xffff0000u;
    float lo = v - __uint_as_float(hi);
    Wh[idx] = (unsigned short)(u >> 16);
    Wl[idx] = (unsigned short)(__float_as_uint(lo) >> 16);
}

// ---------------------------------------------------------------------------
// pre0_gemm_v8 (R7-fixed): BM=16, whole-K in LDS as hi/lo bf16.
//  - Stage: block's 16 rows = ONE contiguous 69,504B span, 17 coalesced
//    float4/thread (the fill-kernel pattern), hi/lo cvt DURING stage (1x per
//    element, not 4x per wave), bank-balanced LDS (stride 1096 bf16).
//  - Compute: 34 tiles, B-frags prefetched into REGISTERS in double-buffered
//    groups of 4 tiles (no serial L2 chain - R7's real bottleneck), 3-pass
//    hi/lo MFMA, near-zero VALU.
//  - 70KB LDS -> 2 blocks/CU; stage/compute overlap across resident blocks.
// Numerics bit-identical to v4-v7 (absmax 0).
// ---------------------------------------------------------------------------
__global__ __launch_bounds__(256, 2) void pre0_gemm_v8(
    const float* __restrict__ X,
    const unsigned short* __restrict__ Wh, const unsigned short* __restrict__ Wl,
    const float* __restrict__ bias, float* __restrict__ out)
{
    __shared__ unsigned short AsH[16 * ASTRIDE];   // 35,072 B
    __shared__ unsigned short AsL[16 * ASTRIDE];   // 35,072 B

    const int tid = threadIdx.x;
    const long m0 = (long)blockIdx.x * 16;

    // ---- stage: contiguous span, all loads issued first
    const float* src = X + m0 * IN_DIM;
    float4 v[17];
    #pragma unroll
    for (int p = 0; p < 17; ++p) {
        int idx = tid + p * 256;
        if (idx < 4344) v[p] = *(const float4*)(src + idx * 4);
    }
    // zero pad k=1086..1087 (1 dword per row per array)
    if (tid < 32) {
        int r = tid & 15;
        if (tid < 16) *(unsigned*)&AsH[r * ASTRIDE + 1086] = 0u;
        else          *(unsigned*)&AsL[r * ASTRIDE + 1086] = 0u;
    }
    #pragma unroll
    for (int p = 0; p < 17; ++p) {
        int idx = tid + p * 256;
        if (idx < 4344) {
            int f2 = idx * 2;                       // float2 pairs never straddle rows (1086/2=543)
            int r0 = f2 / 543,       c0 = (f2 - r0 * 543) * 2;
            int r1 = (f2 + 1) / 543, c1 = ((f2 + 1) - r1 * 543) * 2;
            unsigned u0 = __float_as_uint(v[p].x), u1 = __float_as_uint(v[p].y);
            unsigned h0 = u0 & 0xffff0000u, h1 = u1 & 0xffff0000u;
            float l0 = v[p].x - __uint_as_float(h0);
            float l1 = v[p].y - __uint_as_float(h1);
            *(unsigned*)&AsH[r0 * ASTRIDE + c0] = (u0 >> 16) | h1;
            *(unsigned*)&AsL[r0 * ASTRIDE + c0] =
                (__float_as_uint(l0) >> 16) | (__float_as_uint(l1) & 0xffff0000u);
            unsigned u2 = __float_as_uint(v[p].z), u3 = __float_as_uint(v[p].w);
            unsigned h2 = u2 & 0xffff0000u, h3 = u3 & 0xffff0000u;
            float l2 = v[p].z - __uint_as_float(h2);
            float l3 = v[p].w - __uint_as_float(h3);
            *(unsigned*)&AsH[r1 * ASTRIDE + c1] = (u2 >> 16) | h3;
            *(unsigned*)&AsL[r1 * ASTRIDE + c1] =
                (__float_as_uint(l2) >> 16) | (__float_as_uint(l3) & 0xffff0000u);
        }
    }
    __syncthreads();                        // the only barrier

    // ---- compute: wave wv owns output cols wv*16..+15 (nf=wv)
    const int fr = tid & 15;
    const int kg = (tid >> 4) & 3;
    const int wv = tid >> 6;

    const unsigned short* WhB = Wh + (kg * 64 + wv * 16 + fr) * 8;  // + kt*2048
    const unsigned short* WlB = Wl + (kg * 64 + wv * 16 + fr) * 8;
    const unsigned short* aH = AsH + fr * ASTRIDE + kg * 8;         // + kt*32
    const unsigned short* aL = AsL + fr * ASTRIDE + kg * 8;

    f32x4v acc;
    #pragma unroll
    for (int q = 0; q < 4; ++q) acc[q] = 0.0f;

    bf16x8 bhA[4], blA[4], bhB[4], blB[4];

#define LOADB(BH, BL, BASE) do {                                        \
    _Pragma("unroll")                                                   \
    for (int j = 0; j < 4; ++j) {                                       \
        int kt = (BASE) + j; kt = kt > 33 ? 33 : kt;                    \
        BH[j] = *(const bf16x8*)(WhB + (size_t)kt * 2048);              \
        BL[j] = *(const bf16x8*)(WlB + (size_t)kt * 2048);              \
    }                                                                   \
} while (0)

#define COMP1(BH, BL, J, KT) do {                                       \
    bf16x8 ah = *(const bf16x8*)(aH + (KT) * 32);                       \
    bf16x8 al = *(const bf16x8*)(aL + (KT) * 32);                       \
    acc = __builtin_amdgcn_mfma_f32_16x16x32_bf16(ah, BH[J], acc, 0, 0, 0); \
    acc = __builtin_amdgcn_mfma_f32_16x16x32_bf16(al, BH[J], acc, 0, 0, 0); \
    acc = __builtin_amdgcn_mfma_f32_16x16x32_bf16(ah, BL[J], acc, 0, 0, 0); \
} while (0)

#define COMP4(BH, BL, BASE) do {                                        \
    COMP1(BH, BL, 0, (BASE) + 0);                                       \
    COMP1(BH, BL, 1, (BASE) + 1);                                       \
    COMP1(BH, BL, 2, (BASE) + 2);                                       \
    COMP1(BH, BL, 3, (BASE) + 3);                                       \
} while (0)

    LOADB(bhA, blA, 0);
    #pragma unroll
    for (int i = 0; i < 4; ++i) {
        LOADB(bhB, blB, 8 * i + 4);
        COMP4(bhA, blA, 8 * i);
        LOADB(bhA, blA, 8 * i + 8);     // i=3: tiles 32,33,33,33 (clamped)
        COMP4(bhB, blB, 8 * i + 4);
    }
    // peel tiles 32, 33 (in bhA slots 0,1)
    COMP1(bhA, blA, 0, 32);
    COMP1(bhA, blA, 1, 33);
#undef LOADB
#undef COMP1
#undef COMP4

    // ---- epilogue: +bias, fp32 store. C/D map: col=lane&15, row=(lane>>4)*4+r
    const float bv = bias[wv * 16 + fr];
    #pragma unroll
    for (int q = 0; q < 4; ++q) {
        long row = m0 + kg * 4 + q;
        out[row * 64 + wv * 16 + fr] = acc[q] + bv;
    }
}

// ---------------------------------------------------------------------------
// mega_scan: 4-wave layer pipeline (unchanged — ~45us).
// ---------------------------------------------------------------------------
__global__ __launch_bounds__(256) void mega_scan(
    const float* __restrict__ pre0, const float* __restrict__ whh0,
    const float* __restrict__ wih1, const float* __restrict__ whh1, const float* __restrict__ b1,
    const float* __restrict__ wih2, const float* __restrict__ whh2, const float* __restrict__ b2,
    const float* __restrict__ wih3, const float* __restrict__ whh3, const float* __restrict__ b3,
    const float* __restrict__ w_fc1, const float* __restrict__ b_fc1,
    const float* __restrict__ w_fc2, const float* __restrict__ b_fc2,
    float* __restrict__ out)
{
    __shared__ float buf[3][T_STEPS][16];

    const int b    = blockIdx.x;
    const int tid  = threadIdx.x;
    const int g    = tid & 63;
    const int wv   = tid >> 6;

    bool sel16 = false, sel32 = false;
#if HAVE_PERMLANE_SWAP
    {
        uv2 q16 = __builtin_amdgcn_permlane16_swap((unsigned)g, (unsigned)g, false, false);
        sel16 = (__builtin_amdgcn_readfirstlane((int)q16[1]) == 16);
        uv2 q32 = __builtin_amdgcn_permlane32_swap((unsigned)g, (unsigned)g, false, false);
        sel32 = (__builtin_amdgcn_readfirstlane((int)q32[1]) == 32);
    }
#endif

    const float* wih = nullptr; const float* whh; const float* bias = nullptr;
    if      (wv == 0) { whh = whh0; }
    else if (wv == 1) { wih = wih1; whh = whh1; bias = b1; }
    else if (wv == 2) { wih = wih2; whh = whh2; bias = b2; }
    else              { wih = wih3; whh = whh3; bias = b3; }

    float whh_r[16];
    #pragma unroll
    for (int q = 0; q < 4; ++q)
        *(float4*)&whh_r[q * 4] = *(const float4*)&whh[g * 16 + q * 4];
    float wih_r[16]; float bg = 0.0f;
    if (wv) {
        #pragma unroll
        for (int q = 0; q < 4; ++q)
            *(float4*)&wih_r[q * 4] = *(const float4*)&wih[g * 16 + q * 4];
        bg = bias[g];
    }

    const float* pb = pre0 + (size_t)b * T_STEPS * 64 + g;
    float pc = 0.0f, p1 = 0.0f, p2 = 0.0f;
    if (wv == 0) { pc = pb[0]; p1 = pb[64]; p2 = pb[128]; }

    float hs[16];
    #pragma unroll
    for (int k = 0; k < 16; ++k) hs[k] = 0.0f;
    float c = 0.0f;

    const int q4 = g >> 4;
    const float escale = (q4 == 2) ? -2.8853900817779268f : -1.4426950408889634f;
    const float am = (q4 == 2) ? 2.0f : 1.0f;
    const float aa = (q4 == 2) ? -1.0f : 0.0f;

    for (int tau = 0; tau < T_STEPS + 3; ++tau) {
        __syncthreads();
        const int t = tau - wv;
        if (t >= 0 && t < T_STEPS) {
            float xr[16];
            if (wv) {
                #pragma unroll
                for (int q = 0; q < 4; ++q)
                    *(float4*)&xr[q * 4] = *(const float4*)&buf[wv - 1][t][q * 4];
            }
            float r0 = fmaf(whh_r[0], hs[0], wv ? bg : pc);
            float r1 = whh_r[1] * hs[1];
            float r2 = whh_r[2] * hs[2];
            float r3 = whh_r[3] * hs[3];
            #pragma unroll
            for (int k = 4; k < 16; k += 4) {
                r0 = fmaf(whh_r[k + 0], hs[k + 0], r0);
                r1 = fmaf(whh_r[k + 1], hs[k + 1], r1);
                r2 = fmaf(whh_r[k + 2], hs[k + 2], r2);
                r3 = fmaf(whh_r[k + 3], hs[k + 3], r3);
            }
            float acc = (r0 + r1) + (r2 + r3);
            if (wv) {
                float p0 = wih_r[0] * xr[0];
                float q1 = wih_r[1] * xr[1];
                float q2 = wih_r[2] * xr[2];
                float q3 = wih_r[3] * xr[3];
                #pragma unroll
                for (int k = 4; k < 16; k += 4) {
                    p0 = fmaf(wih_r[k + 0], xr[k + 0], p0);
                    q1 = fmaf(wih_r[k + 1], xr[k + 1], q1);
                    q2 = fmaf(wih_r[k + 2], xr[k + 2], q2);
                    q3 = fmaf(wih_r[k + 3], xr[k + 3], q3);
                }
                acc += (p0 + q1) + (q2 + q3);
            }
            float e = EXP2F(escale * acc);
            float s = __builtin_amdgcn_rcpf(1.0f + e);
            float a = fmaf(am, s, aa);
#if HAVE_PERMLANE_SWAP
            unsigned au = __float_as_uint(a);
            uv2 r16 = __builtin_amdgcn_permlane16_swap(au, au, false, false);
            uv2 r32 = __builtin_amdgcn_permlane32_swap(au, au, false, false);
            unsigned fvu = sel16 ? r16[1] : r16[0];
            unsigned gvu = sel32 ? r32[1] : r32[0];
            uv2 r48 = __builtin_amdgcn_permlane16_swap(gvu, gvu, false, false);
            unsigned ovu = sel16 ? r48[1] : r48[0];
            float fv = __uint_as_float(fvu);
            float gv = __uint_as_float(gvu);
            float ov = __uint_as_float(ovu);
#else
            float fv = __shfl_xor(a, 16, 64);
            float gv = __shfl_xor(a, 32, 64);
            float ov = __shfl_xor(a, 48, 64);
#endif
            c = fmaf(fv, c, a * gv);
            float e2 = EXP2F(-2.8853900817779268f * c);
            float s2 = __builtin_amdgcn_rcpf(1.0f + e2);
            float hn = fmaf(ov + ov, s2, -ov);
            if (wv < 3 && g < 16) buf[wv][t][g] = hn;
            #pragma unroll
            for (int k = 0; k < 16; ++k) hs[k] = rl_f(hn, k);
            if (wv == 0) {
                pc = p1; p1 = p2;
                int tn = t + 3; tn = tn < T_STEPS ? tn : T_STEPS - 1;
                p2 = pb[(size_t)tn * 64];
            }
        }
    }

    if (wv == 3 && g < 16) {
        float a1 = b_fc1[g];
        #pragma unroll
        for (int k = 0; k < 16; ++k) a1 = fmaf(w_fc1[g * 16 + k], hs[k], a1);
        a1 = fmaxf(a1, 0.0f);
        float h1[16];
        #pragma unroll
        for (int k = 0; k < 16; ++k) h1[k] = rl_f(a1, k);
        float lg = -3.0e38f;
        if (g < 15) {
            lg = b_fc2[g];
            #pragma unroll
            for (int k = 0; k < 16; ++k) lg = fmaf(w_fc2[g * 16 + k], h1[k], lg);
        }
        float mx = lg;
        #pragma unroll
        for (int dd = 8; dd >= 1; dd >>= 1) mx = fmaxf(mx, __shfl_xor(mx, dd, 16));
        float ev = (g < 15) ? EXP2F(1.4426950408889634f * (lg - mx)) : 0.0f;
        float sm = ev;
        #pragma unroll
        for (int dd = 8; dd >= 1; dd >>= 1) sm += __shfl_xor(sm, dd, 16);
        if (g < 15) out[b * 15 + g] = ev * __builtin_amdgcn_rcpf(sm);
    }
}

extern "C" void kernel_launch(void* const* d_in, const int* in_sizes, int n_in,
                              void* d_out, int out_size, void* d_ws, size_t ws_size,
                              hipStream_t stream) {
    const float* x    = (const float*)d_in[0];
    const float* wih0 = (const float*)d_in[1];
    const float* whh0 = (const float*)d_in[2];
    const float* b0   = (const float*)d_in[3];
    const float* wih1 = (const float*)d_in[4];
    const float* whh1 = (const float*)d_in[5];
    const float* b1   = (const float*)d_in[6];
    const float* wih2 = (const float*)d_in[7];
    const float* whh2 = (const float*)d_in[8];
    const float* b2   = (const float*)d_in[9];
    const float* wih3 = (const float*)d_in[10];
    const float* whh3 = (const float*)d_in[11];
    const float* b3   = (const float*)d_in[12];
    const float* wfc1 = (const float*)d_in[13];
    const float* bfc1 = (const float*)d_in[14];
    const float* wfc2 = (const float*)d_in[15];
    const float* bfc2 = (const float*)d_in[16];

    float* pre0 = (float*)d_ws;                                       // 13,107,200 B
    unsigned short* Wh = (unsigned short*)((char*)d_ws + 13107200);   // 139,264 B
    unsigned short* Wl = (unsigned short*)((char*)d_ws + 13107200 + 139264);

    prepack_w<<<dim3((KTILES * 4 * 64 * 8 + 255) / 256), dim3(256), 0, stream>>>(wih0, Wh, Wl);
    pre0_gemm_v8<<<dim3(M_TOTAL / 16), dim3(256), 0, stream>>>(x, Wh, Wl, b0, pre0);
    mega_scan<<<dim3(256), dim3(256), 0, stream>>>(pre0, whh0,
        wih1, whh1, b1, wih2, whh2, b2, wih3, whh3, b3,
        wfc1, bfc1, wfc2, bfc2, (float*)d_out);
}